// Round 2
// baseline (815.662 us; speedup 1.0000x reference)
//
#include <hip/hip_runtime.h>
#include <math.h>

typedef float f2v __attribute__((ext_vector_type(2)));
typedef float f4v __attribute__((ext_vector_type(4)));

#define TF 256          // f-tile size
#define NTILE 16        // 4096 / TF
#define FT 36864        // F*T floats per batch (4096*9)

__global__ __launch_bounds__(256, 4) void scorer_kernel(
    const float* __restrict__ x,     // [B, F, T] = [B, 4096, 9]
    const float* __restrict__ th1,   // [2]
    const float* __restrict__ W1,    // [4096, 32]
    const float* __restrict__ b1,    // [32]
    const float* __restrict__ gamma, // [32]
    const float* __restrict__ beta,  // [32]
    const float* __restrict__ th2,   // [2]
    const float* __restrict__ W2,    // [32]
    const float* __restrict__ b2p,   // [1]
    float* __restrict__ out)         // [B, 9]
{
    __shared__ __align__(16) float xl[2 * TF * 9];   // 18432 B
    const int tid = threadIdx.x;
    const int b0 = blockIdx.x * 2;
    const int hg = tid & 7;    // h-group: channels hg*4 .. hg*4+3
    const int fc = tid >> 3;   // f-lane: rows i*32+fc per tile
    const float* xb = x + (size_t)b0 * FT;

    f2v acc[2][9][2];
    #pragma unroll
    for (int b = 0; b < 2; ++b)
        #pragma unroll
        for (int t = 0; t < 9; ++t)
            #pragma unroll
            for (int jv = 0; jv < 2; ++jv) { acc[b][t][jv].x = 0.f; acc[b][t][jv].y = 0.f; }

    const f4v* __restrict__ W1v = (const f4v*)W1;   // index f*8 + hg

    // ---- prologue: prefetch tile 0 into registers ----
    f2v pre[9];
    #pragma unroll
    for (int k = 0; k < 9; ++k) {
        int s = tid + k * 256;                        // 0..2303 f2v units
        const f2v* sp = (s < 1152) ? ((const f2v*)xb) + s
                                   : ((const f2v*)(xb + FT)) + (s - 1152);
        pre[k] = __builtin_nontemporal_load(sp);
    }

    for (int tile = 0; tile < NTILE; ++tile) {
        __syncthreads();   // previous compute done reading xl
        // ---- write prefetched tile into LDS ----
        f2v* dst = (f2v*)xl;
        #pragma unroll
        for (int k = 0; k < 9; ++k) dst[tid + k * 256] = pre[k];
        __syncthreads();
        // ---- issue next tile's loads (latency hides under compute) ----
        if (tile + 1 < NTILE) {
            const int off = (tile + 1) * 1152;        // f2v units
            #pragma unroll
            for (int k = 0; k < 9; ++k) {
                int s = tid + k * 256;
                const f2v* sp = (s < 1152) ? ((const f2v*)xb) + off + s
                                           : ((const f2v*)(xb + FT)) + off + (s - 1152);
                pre[k] = __builtin_nontemporal_load(sp);
            }
        }
        if (tile == 0) {
            // fold plane_rotate(theta1) into the 4 affected f-rows of X
            if (tid < 36) {
                int bb = tid / 18, r = tid % 18, t = r >> 1, p = r & 1;
                float c = cosf(th1[p]), sn = sinf(th1[p]);
                float a  = xl[bb * 2304 + (2 * p) * 9 + t];
                float bv = xl[bb * 2304 + (2 * p + 1) * 9 + t];
                xl[bb * 2304 + (2 * p) * 9 + t]     = c * a - sn * bv;
                xl[bb * 2304 + (2 * p + 1) * 9 + t] = sn * a + c * bv;
            }
            __syncthreads();
        }
        // ---- compute: rows i*32+fc, 9 t, 4 h (as 2x pk), 2 batches ----
        const int fbase = tile * TF;
        f4v w = W1v[(size_t)(fbase + fc) * 8 + hg];
        #pragma unroll
        for (int i = 0; i < 8; ++i) {
            const int row = i * 32 + fc;
            f4v wn = w;
            if (i < 7) wn = W1v[(size_t)(fbase + row + 32) * 8 + hg];
            f2v wlo = {w.x, w.y}, whi = {w.z, w.w};
            const float* xp0 = &xl[row * 9];
            const float* xp1 = xp0 + 2304;
            #pragma unroll
            for (int t = 0; t < 9; ++t) {
                float s0 = xp0[t], s1 = xp1[t];
                f2v x0 = {s0, s0};
                f2v x1 = {s1, s1};
                acc[0][t][0] += x0 * wlo;
                acc[0][t][1] += x0 * whi;
                acc[1][t][0] += x1 * wlo;
                acc[1][t][1] += x1 * whi;
            }
            w = wn;
        }
    }

    __syncthreads();   // all compute done; reuse xl for reduction

    // ---- butterfly reduce over the 8 f-lanes inside each wave ----
    const int wv = tid >> 6;
    const int lane = tid & 63;
    float* redbase = &xl[(wv * 8 + lane) * 72];
    #pragma unroll
    for (int b = 0; b < 2; ++b)
        #pragma unroll
        for (int t = 0; t < 9; ++t)
            #pragma unroll
            for (int jv = 0; jv < 2; ++jv) {
                f2v v = acc[b][t][jv];
                v.x += __shfl_xor(v.x, 8);  v.y += __shfl_xor(v.y, 8);
                v.x += __shfl_xor(v.x, 16); v.y += __shfl_xor(v.y, 16);
                v.x += __shfl_xor(v.x, 32); v.y += __shfl_xor(v.y, 32);
                if (lane < 8) {
                    int idx = b * 36 + t * 4 + jv * 2;
                    redbase[idx]     = v.x;
                    redbase[idx + 1] = v.y;
                }
            }
    __syncthreads();

    // ---- cross-wave sum + bias + modular phase norm -> g in LDS ----
    for (int o = tid; o < 576; o += 256) {
        int h = o & 31;
        int t = (o >> 5) % 9;
        int bb = o / 288;
        int hg2 = h >> 2, j = h & 3;
        int idx = bb * 36 + t * 4 + j;
        float v = xl[(0 * 8 + hg2) * 72 + idx]
                + xl[(1 * 8 + hg2) * 72 + idx]
                + xl[(2 * 8 + hg2) * 72 + idx]
                + xl[(3 * 8 + hg2) * 72 + idx];
        v += b1[h];
        float wr = v - 7.0f * floorf(v / 7.0f + 0.5f);
        float g = gamma[h] * wr + beta[h];
        xl[2304 + bb * 288 + t * 32 + h] = g;
    }
    __syncthreads();

    // ---- rotate(theta2), dot with W2, bias -> scores ----
    if (tid < 18) {
        int bb = tid / 9, t = tid % 9;
        const float* g = &xl[2304 + bb * 288 + t * 32];
        float c0 = cosf(th2[0]), s0r = sinf(th2[0]);
        float c1 = cosf(th2[1]), s1r = sinf(th2[1]);
        float sc = (c0 * g[0] - s0r * g[1]) * W2[0]
                 + (s0r * g[0] + c0 * g[1]) * W2[1]
                 + (c1 * g[2] - s1r * g[3]) * W2[2]
                 + (s1r * g[2] + c1 * g[3]) * W2[3];
        #pragma unroll
        for (int h = 4; h < 32; ++h) sc += g[h] * W2[h];
        sc += b2p[0];
        xl[2880 + bb * 9 + t] = sc;
    }
    __syncthreads();

    // ---- softmax over t=0..8, write output ----
    if (tid < 18) {
        int bb = tid / 9, t = tid % 9;
        const float* sb = &xl[2880 + bb * 9];
        float m = sb[0];
        #pragma unroll
        for (int k = 1; k < 9; ++k) m = fmaxf(m, sb[k]);
        float den = 0.f;
        #pragma unroll
        for (int k = 0; k < 9; ++k) den += expf(sb[k] - m);
        out[(size_t)(b0 + bb) * 9 + t] = expf(sb[t] - m) / den;
    }
}

extern "C" void kernel_launch(void* const* d_in, const int* in_sizes, int n_in,
                              void* d_out, int out_size, void* d_ws, size_t ws_size,
                              hipStream_t stream) {
    const float* x     = (const float*)d_in[0];
    const float* th1   = (const float*)d_in[1];
    const float* W1    = (const float*)d_in[2];
    const float* b1    = (const float*)d_in[3];
    const float* gamma = (const float*)d_in[4];
    const float* beta  = (const float*)d_in[5];
    const float* th2   = (const float*)d_in[6];
    const float* W2    = (const float*)d_in[7];
    const float* b2    = (const float*)d_in[8];
    float* out = (float*)d_out;

    const int B = in_sizes[0] / FT;   // 8192
    dim3 grid(B / 2), block(256);
    hipLaunchKernelGGL(scorer_kernel, grid, block, 0, stream,
                       x, th1, W1, b1, gamma, beta, th2, W2, b2, out);
}

// Round 4
// 439.919 us; speedup vs baseline: 1.8541x; 1.8541x over previous
//
#include <hip/hip_runtime.h>
#include <math.h>

typedef float f2v __attribute__((ext_vector_type(2)));
typedef float f4v __attribute__((ext_vector_type(4)));

#define NTILE 16
#define TILE_F 2304      // floats per batch-tile (256 f rows x 9 t)
#define BUF_F  4608      // floats per dbuf half (2 batches)
#define FT 36864         // floats per batch (4096*9)

// global -> LDS direct DMA. Only HW-verified widths: 16 (m97) and 4 (m03).
// LDS dest = wave-uniform base; HW writes base + lane*width linearly (m104).
#define GL16(gp, lp) \
    __builtin_amdgcn_global_load_lds((const __attribute__((address_space(1))) void*)(gp), \
                                     (__attribute__((address_space(3))) void*)(lp), 16, 0, 0)
#define GL4(gp, lp) \
    __builtin_amdgcn_global_load_lds((const __attribute__((address_space(1))) void*)(gp), \
                                     (__attribute__((address_space(3))) void*)(lp), 4, 0, 0)

__global__ __launch_bounds__(256) void scorer_kernel(
    const float* __restrict__ x,     // [B, 4096, 9]
    const float* __restrict__ th1,   // [2]
    const float* __restrict__ W1,    // [4096, 32]
    const float* __restrict__ b1,    // [32]
    const float* __restrict__ gamma, // [32]
    const float* __restrict__ beta,  // [32]
    const float* __restrict__ th2,   // [2]
    const float* __restrict__ W2,    // [32]
    const float* __restrict__ b2p,   // [1]
    float* __restrict__ out)         // [B, 9]
{
    __shared__ __align__(16) float xl[2 * BUF_F];   // 36864 B, double-buffered
    const int tid = threadIdx.x;
    const int wv  = tid >> 6;          // wave 0..3
    const int hg  = tid & 7;           // h-group: channels hg*4 .. hg*4+3
    const int fc  = tid >> 3;          // 0..31: rows i*32+fc
    const int b0  = blockIdx.x * 2;
    const float* xb = x + (size_t)b0 * FT;

    f2v acc[2][9][2];
    #pragma unroll
    for (int b = 0; b < 2; ++b)
        #pragma unroll
        for (int t = 0; t < 9; ++t) {
            acc[b][t][0] = (f2v){0.f, 0.f};
            acc[b][t][1] = (f2v){0.f, 0.f};
        }

    // ---- per-tile DMA: 2 batches x (2x16B + 1x4B) per thread ----
    #define STAGE(tileidx, lbuf)                                            \
        do {                                                                \
            const float* gt0 = xb + (size_t)(tileidx) * TILE_F;             \
            const float* gt1 = gt0 + FT;                                    \
            float* lb = (lbuf);                                             \
            GL16(gt0 + tid * 4,        lb + wv * 256);                      \
            GL16(gt0 + 1024 + tid * 4, lb + 1024 + wv * 256);               \
            GL4 (gt0 + 2048 + tid,     lb + 2048 + wv * 64);                \
            GL16(gt1 + tid * 4,        lb + TILE_F + wv * 256);             \
            GL16(gt1 + 1024 + tid * 4, lb + TILE_F + 1024 + wv * 256);      \
            GL4 (gt1 + 2048 + tid,     lb + TILE_F + 2048 + wv * 64);       \
        } while (0)

    // ---- prologue: DMA tile 0 into buf0 ----
    STAGE(0, xl);

    int cur = 0;
    for (int tile = 0; tile < NTILE; ++tile) {
        __syncthreads();   // drains vmcnt: buf[cur] landed; buf[cur^1] free
        // ---- issue next tile's DMA; stays in flight under compute ----
        if (tile + 1 < NTILE)
            STAGE(tile + 1, &xl[(cur ^ 1) * BUF_F]);
        if (tile == 0) {
            // fold plane_rotate(theta1) into global f-rows 0..3 (both batches)
            if (tid < 36) {
                int bb = tid / 18, r = tid % 18, t = r >> 1, p = r & 1;
                float c = cosf(th1[p]), sn = sinf(th1[p]);
                float a  = xl[bb * TILE_F + (2 * p) * 9 + t];
                float bv = xl[bb * TILE_F + (2 * p + 1) * 9 + t];
                xl[bb * TILE_F + (2 * p) * 9 + t]     = c * a - sn * bv;
                xl[bb * TILE_F + (2 * p + 1) * 9 + t] = sn * a + c * bv;
            }
            __syncthreads();
        }
        // ---- compute: 8 rows (i*32+fc) x 9 t x 4 h (pk-fma) x 2 batches ----
        const float* xbuf = &xl[cur * BUF_F];
        const size_t fb = (size_t)tile * 256;
        #pragma unroll
        for (int i = 0; i < 8; ++i) {
            const int row = i * 32 + fc;
            f4v wq = ((const f4v*)W1)[(fb + row) * 8 + hg];
            f2v wlo = {wq.x, wq.y}, whi = {wq.z, wq.w};
            const float* xp0 = &xbuf[row * 9];
            const float* xp1 = xp0 + TILE_F;
            #pragma unroll
            for (int t = 0; t < 9; ++t) {
                f2v x0 = {xp0[t], xp0[t]};
                f2v x1 = {xp1[t], xp1[t]};
                acc[0][t][0] += x0 * wlo;
                acc[0][t][1] += x0 * whi;
                acc[1][t][0] += x1 * wlo;
                acc[1][t][1] += x1 * whi;
            }
        }
        cur ^= 1;
    }

    // ---- reduce over fc: butterfly (xor 8,16,32) -> per-wave partials ----
    // red = xl[0..2304): buf0 region; last tile (15) read buf1 — disjoint.
    const int lane = tid & 63;
    float* red = xl;
    float* redbase = &red[(wv * 8 + lane) * 72];
    #pragma unroll
    for (int b = 0; b < 2; ++b)
        #pragma unroll
        for (int t = 0; t < 9; ++t)
            #pragma unroll
            for (int jv = 0; jv < 2; ++jv) {
                f2v v = acc[b][t][jv];
                v.x += __shfl_xor(v.x, 8);  v.y += __shfl_xor(v.y, 8);
                v.x += __shfl_xor(v.x, 16); v.y += __shfl_xor(v.y, 16);
                v.x += __shfl_xor(v.x, 32); v.y += __shfl_xor(v.y, 32);
                if (lane < 8) {
                    int idx = b * 36 + t * 4 + jv * 2;
                    redbase[idx]     = v.x;
                    redbase[idx + 1] = v.y;
                }
            }
    __syncthreads();

    // ---- cross-wave sum + bias + modular phase norm -> g at xl[2304..] ----
    for (int o = tid; o < 576; o += 256) {
        int h = o & 31;
        int t = (o >> 5) % 9;
        int bb = o / 288;
        int hg2 = h >> 2, j = h & 3;
        int idx = bb * 36 + t * 4 + j;
        float v = red[(0 * 8 + hg2) * 72 + idx]
                + red[(1 * 8 + hg2) * 72 + idx]
                + red[(2 * 8 + hg2) * 72 + idx]
                + red[(3 * 8 + hg2) * 72 + idx];
        v += b1[h];
        float wr = v - 7.0f * floorf(v / 7.0f + 0.5f);
        xl[2304 + bb * 288 + t * 32 + h] = gamma[h] * wr + beta[h];
    }
    __syncthreads();

    // ---- rotate(theta2), dot with W2, bias -> scores ----
    if (tid < 18) {
        int bb = tid / 9, t = tid % 9;
        const float* g = &xl[2304 + bb * 288 + t * 32];
        float c0 = cosf(th2[0]), s0 = sinf(th2[0]);
        float c1 = cosf(th2[1]), s1 = sinf(th2[1]);
        float sc = (c0 * g[0] - s0 * g[1]) * W2[0]
                 + (s0 * g[0] + c0 * g[1]) * W2[1]
                 + (c1 * g[2] - s1 * g[3]) * W2[2]
                 + (s1 * g[2] + c1 * g[3]) * W2[3];
        #pragma unroll
        for (int h = 4; h < 32; ++h) sc += g[h] * W2[h];
        sc += b2p[0];
        xl[2880 + bb * 9 + t] = sc;
    }
    __syncthreads();

    // ---- softmax over t=0..8, write output ----
    if (tid < 18) {
        int bb = tid / 9, t = tid % 9;
        const float* sb = &xl[2880 + bb * 9];
        float m = sb[0];
        #pragma unroll
        for (int k = 1; k < 9; ++k) m = fmaxf(m, sb[k]);
        float den = 0.f;
        #pragma unroll
        for (int k = 0; k < 9; ++k) den += expf(sb[k] - m);
        out[(size_t)(b0 + bb) * 9 + t] = expf(sb[t] - m) / den;
    }
}

extern "C" void kernel_launch(void* const* d_in, const int* in_sizes, int n_in,
                              void* d_out, int out_size, void* d_ws, size_t ws_size,
                              hipStream_t stream) {
    const float* x     = (const float*)d_in[0];
    const float* th1   = (const float*)d_in[1];
    const float* W1    = (const float*)d_in[2];
    const float* b1    = (const float*)d_in[3];
    const float* gamma = (const float*)d_in[4];
    const float* beta  = (const float*)d_in[5];
    const float* th2   = (const float*)d_in[6];
    const float* W2    = (const float*)d_in[7];
    const float* b2    = (const float*)d_in[8];
    float* out = (float*)d_out;

    const int B = in_sizes[0] / FT;   // 8192
    dim3 grid(B / 2), block(256);
    hipLaunchKernelGGL(scorer_kernel, grid, block, 0, stream,
                       x, th1, W1, b1, gamma, beta, th2, W2, b2, out);
}

// Round 5
// 425.960 us; speedup vs baseline: 1.9149x; 1.0328x over previous
//
#include <hip/hip_runtime.h>
#include <math.h>

typedef float f2v __attribute__((ext_vector_type(2)));
typedef float f4v __attribute__((ext_vector_type(4)));

#define NTILE 16
#define TILE_W 2304      // words per tile (256 f rows x 9 t)
#define FT 36864         // words per batch (4096*9)

__global__ __launch_bounds__(256) void scorer_kernel(
    const float* __restrict__ x,     // [B, 4096, 9]
    const float* __restrict__ th1,   // [2]
    const float* __restrict__ W1,    // [4096, 32]
    const float* __restrict__ b1,    // [32]
    const float* __restrict__ gamma, // [32]
    const float* __restrict__ beta,  // [32]
    const float* __restrict__ th2,   // [2]
    const float* __restrict__ W2,    // [32]
    const float* __restrict__ b2p,   // [1]
    float* __restrict__ out)         // [B, 9]
{
    // double-buffered transposed tile: buf[k][t][f], f = 0..255
    __shared__ __align__(16) float xl[2 * TILE_W];   // 18432 B
    const int tid = threadIdx.x;
    const int hg  = tid & 7;           // h-group: channels hg*4..hg*4+3
    const int fc  = tid >> 3;          // 0..31: rows fc*8..fc*8+7
    const int wv  = tid >> 6;          // wave 0..3
    const float* xb = x + (size_t)blockIdx.x * FT;

    f2v acc[9][2];
    #pragma unroll
    for (int t = 0; t < 9; ++t) {
        acc[t][0] = (f2v){0.f, 0.f};
        acc[t][1] = (f2v){0.f, 0.f};
    }

    // precompute transpose-scatter LDS addresses: flat tile word w -> [t][f]
    int laddr[9];
    #pragma unroll
    for (int j = 0; j < 9; ++j) {
        int w = (j < 4) ? tid * 4 + j
              : (j < 8) ? 1024 + tid * 4 + (j - 4)
                        : 2048 + tid;
        int f = (unsigned)w / 9u;
        int t = w - 9 * f;
        laddr[j] = t * 256 + f;
    }

    // ---- prologue: coalesced load of tile 0 into regs ----
    f4v s04 = __builtin_nontemporal_load((const f4v*)(xb + tid * 4));
    f4v s47 = __builtin_nontemporal_load((const f4v*)(xb + 1024 + tid * 4));
    float s8 = __builtin_nontemporal_load(xb + 2048 + tid);

    const f4v* __restrict__ W1v = (const f4v*)W1;
    int cur = 0;
    for (int tile = 0; tile < NTILE; ++tile) {
        __syncthreads();   // #1: buf[cur] free; s regs landed (issued a full phase ago)
        float* lb = &xl[cur * TILE_W];
        lb[laddr[0]] = s04.x; lb[laddr[1]] = s04.y;
        lb[laddr[2]] = s04.z; lb[laddr[3]] = s04.w;
        lb[laddr[4]] = s47.x; lb[laddr[5]] = s47.y;
        lb[laddr[6]] = s47.z; lb[laddr[7]] = s47.w;
        lb[laddr[8]] = s8;
        __syncthreads();   // #2: buf[cur] readable; vmcnt empty here -> no stall
        // ---- issue next tile's loads AFTER #2: drain happens at next #1 ----
        if (tile + 1 < NTILE) {
            const float* gt = xb + (size_t)(tile + 1) * TILE_W;
            s04 = __builtin_nontemporal_load((const f4v*)(gt + tid * 4));
            s47 = __builtin_nontemporal_load((const f4v*)(gt + 1024 + tid * 4));
            s8  = __builtin_nontemporal_load(gt + 2048 + tid);
        }
        if (tile == 0) {
            // fold plane_rotate(theta1): global f-rows 0..3 -> [t][0..3]
            if (tid < 18) {
                int p = tid / 9, t = tid - p * 9;
                float c = cosf(th1[p]), sn = sinf(th1[p]);
                float a  = xl[t * 256 + 2 * p];
                float bv = xl[t * 256 + 2 * p + 1];
                xl[t * 256 + 2 * p]     = c * a - sn * bv;
                xl[t * 256 + 2 * p + 1] = sn * a + c * bv;
            }
            __syncthreads();
        }
        // ---- compute: hoist 8 W1 rows, then 9 t x 2 b128 x 16 pk-fma ----
        const int fb = tile * 256;
        f2v wlo[8], whi[8];
        #pragma unroll
        for (int i = 0; i < 8; ++i) {
            f4v wq = W1v[(size_t)(fb + fc * 8 + i) * 8 + hg];
            wlo[i] = (f2v){wq.x, wq.y};
            whi[i] = (f2v){wq.z, wq.w};
        }
        const float* xr = &xl[cur * TILE_W + fc * 8];
        #pragma unroll
        for (int t = 0; t < 9; ++t) {
            f4v xa = *(const f4v*)(xr + t * 256);
            f4v xc = *(const f4v*)(xr + t * 256 + 4);
            acc[t][0] += (f2v){xa.x, xa.x} * wlo[0]; acc[t][1] += (f2v){xa.x, xa.x} * whi[0];
            acc[t][0] += (f2v){xa.y, xa.y} * wlo[1]; acc[t][1] += (f2v){xa.y, xa.y} * whi[1];
            acc[t][0] += (f2v){xa.z, xa.z} * wlo[2]; acc[t][1] += (f2v){xa.z, xa.z} * whi[2];
            acc[t][0] += (f2v){xa.w, xa.w} * wlo[3]; acc[t][1] += (f2v){xa.w, xa.w} * whi[3];
            acc[t][0] += (f2v){xc.x, xc.x} * wlo[4]; acc[t][1] += (f2v){xc.x, xc.x} * whi[4];
            acc[t][0] += (f2v){xc.y, xc.y} * wlo[5]; acc[t][1] += (f2v){xc.y, xc.y} * whi[5];
            acc[t][0] += (f2v){xc.z, xc.z} * wlo[6]; acc[t][1] += (f2v){xc.z, xc.z} * whi[6];
            acc[t][0] += (f2v){xc.w, xc.w} * wlo[7]; acc[t][1] += (f2v){xc.w, xc.w} * whi[7];
        }
        cur ^= 1;
    }

    // ---- reduce over fc: butterfly (xor 8,16,32) -> per-wave partials ----
    // red = xl[0..1152) (buf0); tile 15 read buf1 -> disjoint.
    const int lane = tid & 63;
    float* red = xl;
    float* redbase = &red[(wv * 8 + lane) * 36];
    #pragma unroll
    for (int t = 0; t < 9; ++t)
        #pragma unroll
        for (int jv = 0; jv < 2; ++jv) {
            f2v v = acc[t][jv];
            v.x += __shfl_xor(v.x, 8);  v.y += __shfl_xor(v.y, 8);
            v.x += __shfl_xor(v.x, 16); v.y += __shfl_xor(v.y, 16);
            v.x += __shfl_xor(v.x, 32); v.y += __shfl_xor(v.y, 32);
            if (lane < 8) {
                redbase[t * 4 + jv * 2]     = v.x;
                redbase[t * 4 + jv * 2 + 1] = v.y;
            }
        }
    __syncthreads();

    // ---- cross-wave sum + bias + modular phase norm -> g at xl[1200..) ----
    for (int o = tid; o < 288; o += 256) {
        int h = o & 31, t = o >> 5;
        int hg2 = h >> 2, j = h & 3;
        int idx = t * 4 + j;
        float v = red[(0 * 8 + hg2) * 36 + idx]
                + red[(1 * 8 + hg2) * 36 + idx]
                + red[(2 * 8 + hg2) * 36 + idx]
                + red[(3 * 8 + hg2) * 36 + idx];
        v += b1[h];
        float wr = v - 7.0f * floorf(v / 7.0f + 0.5f);
        xl[1200 + o] = gamma[h] * wr + beta[h];   // o == t*32 + h
    }
    __syncthreads();

    // ---- rotate(theta2), dot with W2, bias -> scores ----
    if (tid < 9) {
        const float* g = &xl[1200 + tid * 32];
        float c0 = cosf(th2[0]), s0 = sinf(th2[0]);
        float c1 = cosf(th2[1]), s1 = sinf(th2[1]);
        float sc = (c0 * g[0] - s0 * g[1]) * W2[0]
                 + (s0 * g[0] + c0 * g[1]) * W2[1]
                 + (c1 * g[2] - s1 * g[3]) * W2[2]
                 + (s1 * g[2] + c1 * g[3]) * W2[3];
        #pragma unroll
        for (int h = 4; h < 32; ++h) sc += g[h] * W2[h];
        sc += b2p[0];
        xl[1500 + tid] = sc;
    }
    __syncthreads();

    // ---- softmax over t, write out ----
    if (tid < 9) {
        const float* sb = &xl[1500];
        float m = sb[0];
        #pragma unroll
        for (int k = 1; k < 9; ++k) m = fmaxf(m, sb[k]);
        float den = 0.f;
        #pragma unroll
        for (int k = 0; k < 9; ++k) den += expf(sb[k] - m);
        out[(size_t)blockIdx.x * 9 + tid] = expf(sb[tid] - m) / den;
    }
}

extern "C" void kernel_launch(void* const* d_in, const int* in_sizes, int n_in,
                              void* d_out, int out_size, void* d_ws, size_t ws_size,
                              hipStream_t stream) {
    const float* x     = (const float*)d_in[0];
    const float* th1   = (const float*)d_in[1];
    const float* W1    = (const float*)d_in[2];
    const float* b1    = (const float*)d_in[3];
    const float* gamma = (const float*)d_in[4];
    const float* beta  = (const float*)d_in[5];
    const float* th2   = (const float*)d_in[6];
    const float* W2    = (const float*)d_in[7];
    const float* b2    = (const float*)d_in[8];
    float* out = (float*)d_out;

    const int B = in_sizes[0] / FT;   // 8192
    dim3 grid(B), block(256);
    hipLaunchKernelGGL(scorer_kernel, grid, block, 0, stream,
                       x, th1, W1, b1, gamma, beta, th2, W2, b2, out);
}